// Round 1
// baseline (136.825 us; speedup 1.0000x reference)
//
#include <hip/hip_runtime.h>

// SelfMixing: CG tensor-product self-coupling, diagonal in channel.
// Key insight: all paths couple channel i of block l1 with channel i of block l2
// and write channel i of block l3 -> each (row, channel) is independent.
// CG tensors computed at COMPILE TIME via constexpr Racah + complex->real basis
// change (mirrors the reference _cg_complex/_U/_real_cg exactly) so weights fold
// into immediates and zero terms are eliminated.

namespace cgc {

struct cplx { double re, im; };
constexpr cplx cmul(cplx a, cplx b){ return {a.re*b.re - a.im*b.im, a.re*b.im + a.im*b.re}; }

constexpr double cfact(int n){ double r = 1.0; for (int i = 2; i <= n; ++i) r *= i; return r; }
constexpr double cabsd(double x){ return x < 0 ? -x : x; }

constexpr double csqrtd(double x){
  if (x <= 0.0) return 0.0;
  double g = x > 1.0 ? x : 1.0;
  for (int i = 0; i < 48; ++i) g = 0.5*(g + x/g);
  return g;
}

constexpr double SQRT2 = csqrtd(2.0);

constexpr double cg_complex(int l1,int m1,int l2,int m2,int l3,int m3){
  if (m1 + m2 != m3) return 0.0;
  int lo = l1 > l2 ? l1 - l2 : l2 - l1;
  if (l3 < lo || l3 > l1 + l2) return 0.0;
  double pre = csqrtd((2*l3+1) * cfact(l1+l2-l3)*cfact(l1-l2+l3)*cfact(-l1+l2+l3)/cfact(l1+l2+l3+1));
  pre *= csqrtd(cfact(l1+m1)*cfact(l1-m1)*cfact(l2+m2)*cfact(l2-m2)*cfact(l3+m3)*cfact(l3-m3));
  int kmin = 0;
  if (l2-l3-m1 > kmin) kmin = l2-l3-m1;
  if (l1-l3+m2 > kmin) kmin = l1-l3+m2;
  int kmax = l1+l2-l3;
  if (l1-m1 < kmax) kmax = l1-m1;
  if (l2+m2 < kmax) kmax = l2+m2;
  double s = 0.0;
  for (int k = kmin; k <= kmax; ++k){
    double d = cfact(k)*cfact(l1+l2-l3-k)*cfact(l1-m1-k)*cfact(l2+m2-k)
             * cfact(l3-l2+m1+k)*cfact(l3-l1-m2+k);
    s += ((k & 1) ? -1.0 : 1.0) / d;
  }
  return pre * s;
}

// U[r][c]: rows = real m' (r = m'+l), cols = complex m (c = m+l)
constexpr cplx Uent(int l, int r, int c){
  int m = r - l;
  if (m > 0){
    if (c ==  m + l) return { ((m & 1) ? -1.0 : 1.0)/SQRT2, 0.0 };
    if (c == -m + l) return { 1.0/SQRT2, 0.0 };
    return {0.0, 0.0};
  } else if (m == 0){
    if (c == l) return {1.0, 0.0};
    return {0.0, 0.0};
  } else {
    int ma = -m;
    if (c ==  m + l) return { 0.0, 1.0/SQRT2 };                       // 1j/sqrt2
    if (c == -m + l) return { 0.0, -(((ma & 1) ? -1.0 : 1.0))/SQRT2 };// -1j*(-1)^m/sqrt2
    return {0.0, 0.0};
  }
}

template<int L1,int L2,int L3>
struct CGData { float w[(2*L1+1)*(2*L2+1)*(2*L3+1)]; };

template<int L1,int L2,int L3>
constexpr CGData<L1,L2,L3> make_cg(){
  constexpr int D1 = 2*L1+1, D2 = 2*L2+1, D3 = 2*L3+1;
  // precompute U matrices (U3 conjugated)
  cplx U1[D1*D1] = {}; cplx U2[D2*D2] = {}; cplx U3c[D3*D3] = {};
  for (int r = 0; r < D1; ++r) for (int c = 0; c < D1; ++c) U1[r*D1+c] = Uent(L1, r, c);
  for (int r = 0; r < D2; ++r) for (int c = 0; c < D2; ++c) U2[r*D2+c] = Uent(L2, r, c);
  for (int r = 0; r < D3; ++r) for (int c = 0; c < D3; ++c){
    cplx u = Uent(L3, r, c); u.im = -u.im; U3c[r*D3+c] = u;
  }
  // complex CG
  double Cc[D1*D2*D3] = {};
  for (int m1 = -L1; m1 <= L1; ++m1)
    for (int m2 = -L2; m2 <= L2; ++m2){
      int m3 = m1 + m2;
      if (m3 < -L3 || m3 > L3) continue;
      Cc[((m1+L1)*D2 + (m2+L2))*D3 + (m3+L3)] = cg_complex(L1,m1,L2,m2,L3,m3);
    }
  // transform: T[a][b][c] = sum_{m,n,o} U1[a][m] U2[b][n] conj(U3)[c][o] Cc[m][n][o]
  double re[D1*D2*D3] = {}; double im[D1*D2*D3] = {};
  for (int a = 0; a < D1; ++a)
    for (int b = 0; b < D2; ++b)
      for (int c = 0; c < D3; ++c){
        double sre = 0.0, sim = 0.0;
        for (int m = 0; m < D1; ++m)
          for (int n = 0; n < D2; ++n){
            int o = m + n - L1 - L2 + L3;   // only nonzero Cc slice
            if (o < 0 || o >= D3) continue;
            double cc = Cc[(m*D2+n)*D3 + o];
            if (cc == 0.0) continue;
            cplx p = cmul(cmul(U1[a*D1+m], U2[b*D2+n]), U3c[c*D3+o]);
            sre += p.re * cc; sim += p.im * cc;
          }
        re[(a*D2+b)*D3+c] = sre; im[(a*D2+b)*D3+c] = sim;
      }
  double mre = 0.0, mim = 0.0;
  for (int k = 0; k < D1*D2*D3; ++k){
    if (cabsd(re[k]) > mre) mre = cabsd(re[k]);
    if (cabsd(im[k]) > mim) mim = cabsd(im[k]);
  }
  CGData<L1,L2,L3> outv{};
  for (int k = 0; k < D1*D2*D3; ++k){
    double v = (mim > mre) ? im[k] : re[k];
    outv.w[k] = (cabsd(v) < 1e-10) ? 0.0f : (float)v;
  }
  return outv;
}

} // namespace cgc

template<int L1,int L2,int L3>
__device__ __forceinline__ void tp_path(const float* xa, const float* xb, float cmix, float* acc){
  constexpr cgc::CGData<L1,L2,L3> cg = cgc::make_cg<L1,L2,L3>();
  constexpr int D1 = 2*L1+1, D2 = 2*L2+1, D3 = 2*L3+1;
  #pragma unroll
  for (int a = 0; a < D1; ++a){
    #pragma unroll
    for (int b = 0; b < D2; ++b){
      const float pr = xa[a] * xb[b];
      #pragma unroll
      for (int m = 0; m < D3; ++m){
        const float W = cg.w[(a*D2+b)*D3 + m];
        if (W != 0.0f) acc[m] += (cmix * W) * pr;   // folded at compile time; zeros DCE'd
      }
    }
  }
}

// Layout constants (match reference):
// OFF_IN  = [0, 64, 208, 368]; OFF_OUT = [0, 64, 208, 448, 672]
// mix bases per path order:
//  (0,0,0):0 (0,1,1):64 (0,2,2):112 (1,0,1):144 (1,1,0):192 (1,1,1):240 (1,1,2):288
//  (1,2,1):336 (1,2,2):368 (1,2,3):400 (2,0,2):432 (2,1,1):464 (2,1,2):496 (2,1,3):528
//  (2,2,0):560 (2,2,1):592 (2,2,2):624 (2,2,3):656
// keep chan: l0 -> i, l1 -> 64+i, l2 -> 112+i

__global__ __launch_bounds__(256) void selfmix_kernel(
    const float* __restrict__ x, const float* __restrict__ keep,
    const float* __restrict__ mix, float* __restrict__ out, int n)
{
  const long long gid = (long long)blockIdx.x * 256 + threadIdx.x;
  const long long nA = (long long)n * 32;   // class A threads: channels 0..31 (all l)
  const long long nB = (long long)n * 16;   // class B: channels 32..47 (l0,l1); class C: 48..63 (l0)

  if (gid < nA){
    const int i   = (int)(gid & 31);
    const int row = (int)(gid >> 5);
    const float* xr = x + (long long)row * 368;
    float*     orow = out + (long long)row * 672;
    float s = xr[i];
    float p[3], d[5];
    #pragma unroll
    for (int k = 0; k < 3; ++k) p[k] = xr[64 + i*3 + k];
    #pragma unroll
    for (int k = 0; k < 5; ++k) d[k] = xr[208 + i*5 + k];

    float o0 = 0.f;
    float o1[3] = {0.f,0.f,0.f};
    float o2[5] = {0.f,0.f,0.f,0.f,0.f};
    float o3[7] = {0.f,0.f,0.f,0.f,0.f,0.f,0.f};

    tp_path<0,0,0>(&s,&s, 0.5f*mix[  0+i], &o0);
    tp_path<0,1,1>(&s, p, 0.5f*mix[ 64+i],  o1);
    tp_path<0,2,2>(&s, d, 0.5f*mix[112+i],  o2);
    tp_path<1,0,1>( p,&s, 0.5f*mix[144+i],  o1);
    tp_path<1,1,0>( p, p, 0.5f*mix[192+i], &o0);
    tp_path<1,1,1>( p, p, 0.5f*mix[240+i],  o1);
    tp_path<1,1,2>( p, p, 0.5f*mix[288+i],  o2);
    tp_path<1,2,1>( p, d, 0.5f*mix[336+i],  o1);
    tp_path<1,2,2>( p, d, 0.5f*mix[368+i],  o2);
    tp_path<1,2,3>( p, d, 0.5f*mix[400+i],  o3);
    tp_path<2,0,2>( d,&s, 0.5f*mix[432+i],  o2);
    tp_path<2,1,1>( d, p, 0.5f*mix[464+i],  o1);
    tp_path<2,1,2>( d, p, 0.5f*mix[496+i],  o2);
    tp_path<2,1,3>( d, p, 0.5f*mix[528+i],  o3);
    tp_path<2,2,0>( d, d, 0.5f*mix[560+i], &o0);
    tp_path<2,2,1>( d, d, 0.5f*mix[592+i],  o1);
    tp_path<2,2,2>( d, d, 0.5f*mix[624+i],  o2);
    tp_path<2,2,3>( d, d, 0.5f*mix[656+i],  o3);

    // keep path
    o0 += keep[i] * s;
    const float k1 = keep[64+i], k2 = keep[112+i];
    #pragma unroll
    for (int k = 0; k < 3; ++k) o1[k] += k1 * p[k];
    #pragma unroll
    for (int k = 0; k < 5; ++k) o2[k] += k2 * d[k];

    orow[i] = o0;
    #pragma unroll
    for (int k = 0; k < 3; ++k) orow[ 64 + i*3 + k] = o1[k];
    #pragma unroll
    for (int k = 0; k < 5; ++k) orow[208 + i*5 + k] = o2[k];
    #pragma unroll
    for (int k = 0; k < 7; ++k) orow[448 + i*7 + k] = o3[k];

  } else if (gid < nA + nB){
    const long long t = gid - nA;
    const int i   = 32 + (int)(t & 15);
    const int row = (int)(t >> 4);
    const float* xr = x + (long long)row * 368;
    float*     orow = out + (long long)row * 672;
    float s = xr[i];
    float p[3];
    #pragma unroll
    for (int k = 0; k < 3; ++k) p[k] = xr[64 + i*3 + k];

    float o0 = 0.f;
    float o1[3] = {0.f,0.f,0.f};
    float o2[5] = {0.f,0.f,0.f,0.f,0.f};

    tp_path<0,0,0>(&s,&s, 0.5f*mix[  0+i], &o0);
    tp_path<0,1,1>(&s, p, 0.5f*mix[ 64+i],  o1);
    tp_path<1,0,1>( p,&s, 0.5f*mix[144+i],  o1);
    tp_path<1,1,0>( p, p, 0.5f*mix[192+i], &o0);
    tp_path<1,1,1>( p, p, 0.5f*mix[240+i],  o1);
    tp_path<1,1,2>( p, p, 0.5f*mix[288+i],  o2);

    o0 += keep[i] * s;
    const float k1 = keep[64+i];
    #pragma unroll
    for (int k = 0; k < 3; ++k) o1[k] += k1 * p[k];

    orow[i] = o0;
    #pragma unroll
    for (int k = 0; k < 3; ++k) orow[ 64 + i*3 + k] = o1[k];
    #pragma unroll
    for (int k = 0; k < 5; ++k) orow[208 + i*5 + k] = o2[k];

  } else if (gid < nA + 2*nB){
    const long long t = gid - nA - nB;
    const int i   = 48 + (int)(t & 15);
    const int row = (int)(t >> 4);
    const float* xr = x + (long long)row * 368;
    float s = xr[i];
    float o0 = 0.f;
    tp_path<0,0,0>(&s,&s, 0.5f*mix[0+i], &o0);
    o0 += keep[i] * s;
    out[(long long)row * 672 + i] = o0;
  }
}

extern "C" void kernel_launch(void* const* d_in, const int* in_sizes, int n_in,
                              void* d_out, int out_size, void* d_ws, size_t ws_size,
                              hipStream_t stream)
{
  const float* x    = (const float*)d_in[0];
  const float* keep = (const float*)d_in[1];
  const float* mix  = (const float*)d_in[2];
  float* out = (float*)d_out;
  const int n = in_sizes[0] / 368;          // 32768
  const long long total = (long long)n * 64; // one thread per (row, channel-slot)
  const int blocks = (int)((total + 255) / 256);
  selfmix_kernel<<<blocks, 256, 0, stream>>>(x, keep, mix, out, n);
}